// Round 4
// baseline (7351.223 us; speedup 1.0000x reference)
//
#include <hip/hip_runtime.h>
#include <hip/hip_bf16.h>

typedef __bf16 bf16x8 __attribute__((ext_vector_type(8)));
typedef float f32x4 __attribute__((ext_vector_type(4)));

#define MFMA_B16(a,b,c) __builtin_amdgcn_mfma_f32_16x16x32_bf16((a),(b),(c),0,0,0)

// Tsit5 coefficients
#define A21f 0.161f
#define A31f (-0.008480655492356989f)
#define A32f 0.335480655492357f
#define A41f 2.8971530571054935f
#define A42f (-6.359448489975075f)
#define A43f 4.3622954328695815f
#define A51f 5.325864828439257f
#define A52f (-11.748883564062828f)
#define A53f 7.4955393428898365f
#define A54f (-0.09249506636175525f)
#define A61f 5.86145544294642f
#define A62f (-12.92096931784711f)
#define A63f 8.159367898576159f
#define A64f (-0.071584973281401f)
#define A65f (-0.028269050394068383f)
#define B1f 0.09646076681806523f
#define B2f 0.01f
#define B3f 0.4798896504144996f
#define B4f 1.379008574103742f
#define B5f (-3.290069515436081f)
#define B6f 2.324710524099774f

constexpr int T_SAVE = 128;
constexpr int DIM = 64;
constexpr int HID = 256;

__device__ __forceinline__ float fast_exp2(float x){
#if __has_builtin(__builtin_amdgcn_exp2f)
  return __builtin_amdgcn_exp2f(x);
#else
  return exp2f(x);
#endif
}
__device__ __forceinline__ float fast_rcp(float x){
#if __has_builtin(__builtin_amdgcn_rcpf)
  return __builtin_amdgcn_rcpf(x);
#else
  return 1.0f / x;
#endif
}
__device__ __forceinline__ float tanh_fast(float x){
  float t = fast_exp2(x * 2.8853900817779268f);
  return 1.0f - 2.0f * fast_rcp(t + 1.0f);
}
__device__ __forceinline__ f32x4 splat4(float x){ return f32x4{x,x,x,x}; }

// 8 waves (512 thr) / block, 16 batch rows / block, 2 waves/SIMD.
// 2 barriers per feval (Y-ready, H-ready). No partial exchange:
// Layer1: wave w owns hidden tiles {2w, 2w+1} (12 MFMA).
// Layer2: wave w computes FULL K=256 for col-tile (w&3) (24 MFMA) -> kout
//         lands in-register, bitwise-identical in pair (w, w^4).
// State replicated in the pair; w<4 writes Yh (+out), w>=4 writes Yl.
__global__ __launch_bounds__(512, 2)
void node_tsit5_kernel(const float* __restrict__ y0, const float* __restrict__ ts,
                       const float* __restrict__ W1g, const float* __restrict__ b1g,
                       const float* __restrict__ W2g, const float* __restrict__ b2g,
                       const int* __restrict__ nsub_p, float* __restrict__ out)
{
  const int tid = (int)threadIdx.x;
  const int w   = tid >> 6;   // wave 0..7
  const int l   = tid & 63;   // lane
  const int c   = l & 15;
  const int g   = l >> 4;
  const int wq  = w & 3;      // output col-tile
  const bool hiW = (w < 4);
  const int rowbase = (int)blockIdx.x * 16;

  __shared__ __align__(16) __bf16 Yh[2*64*8];
  __shared__ __align__(16) __bf16 Yl[2*64*8];
  __shared__ __align__(16) __bf16 Hh[8*64*8];
  __shared__ __align__(16) __bf16 Hl[8*64*8];
  __shared__ float ts_s[T_SAVE];

  if (tid < T_SAVE) ts_s[tid] = ts[tid];

  const int nsub = nsub_p[0];

  // ---- weight fragments, pre-split into (hi, lo) bf16, in registers ----
  bf16x8 w1h[2][2], w1l[2][2];           // [tile][ks]
#pragma unroll
  for (int nt = 0; nt < 2; ++nt) {
    const int col = (2*w + nt)*16 + c;
#pragma unroll
    for (int ks = 0; ks < 2; ++ks)
#pragma unroll
      for (int j = 0; j < 8; ++j) {
        float v = W1g[(ks*32 + g*8 + j)*HID + col];
        __bf16 hi = (__bf16)v;
        w1h[nt][ks][j] = hi;
        w1l[nt][ks][j] = (__bf16)(v - (float)hi);
      }
  }
  bf16x8 w2h[8], w2l[8];                 // full K for own col-tile
#pragma unroll
  for (int ks = 0; ks < 8; ++ks)
#pragma unroll
    for (int j = 0; j < 8; ++j) {
      float v = W2g[(ks*32 + g*8 + j)*DIM + (wq*16 + c)];
      __bf16 hi = (__bf16)v;
      w2h[ks][j] = hi;
      w2l[ks][j] = (__bf16)(v - (float)hi);
    }
  float b1v[2];
#pragma unroll
  for (int nt = 0; nt < 2; ++nt) b1v[nt] = b1g[(2*w + nt)*16 + c];
  const float b2v = b2g[wq*16 + c];

  const int d_    = wq*16 + c;             // this lane's state dim
  const int physL = l ^ ((l >> 3) & 3);    // swizzled read chunk

  int yoff[4];
#pragma unroll
  for (int s = 0; s < 4; ++s) {
    int row = 4*g + s;
    int lp  = row | (((d_ >> 3) & 3) << 4);
    int ph  = lp ^ ((lp >> 3) & 3);
    yoff[s] = (d_ >> 5)*512 + ph*8 + (d_ & 7);
  }
  int hoff[2][4];
#pragma unroll
  for (int nt = 0; nt < 2; ++nt) {
    int jcol = (2*w + nt)*16 + c;
#pragma unroll
    for (int r = 0; r < 4; ++r) {
      int row = 4*g + r;
      int lp  = row | (((jcol >> 3) & 3) << 4);
      int ph  = lp ^ ((lp >> 3) & 3);
      hoff[nt][r] = (jcol >> 5)*512 + ph*8 + (jcol & 7);
    }
  }

  // ---- initial state (replicated in pair); emit t=0 ----
  f32x4 y4;
#pragma unroll
  for (int s = 0; s < 4; ++s) {
    int row = rowbase + 4*g + s;
    y4[s] = y0[row*DIM + d_];
    if (hiW) out[(size_t)row*(T_SAVE*DIM) + d_] = y4[s];
  }
  __syncthreads();   // ts_s ready

  f32x4 ysv = y4;

  // one evaluation of f(ysv): Y-stage, bar, L1+tanh+H-stage, bar, L2 full-K
  auto feval = [&]() -> f32x4 {
    if (hiW) {
#pragma unroll
      for (int s = 0; s < 4; ++s) Yh[yoff[s]] = (__bf16)ysv[s];
    } else {
#pragma unroll
      for (int s = 0; s < 4; ++s) {
        float hi = (float)(__bf16)ysv[s];
        Yl[yoff[s]] = (__bf16)(ysv[s] - hi);
      }
    }
    __syncthreads();                      // bar1: Y ready
    bf16x8 ah0 = *(const bf16x8*)&Yh[physL*8];
    bf16x8 ah1 = *(const bf16x8*)&Yh[512 + physL*8];
    bf16x8 al0 = *(const bf16x8*)&Yl[physL*8];
    bf16x8 al1 = *(const bf16x8*)&Yl[512 + physL*8];
    f32x4 p0 = {0.f,0.f,0.f,0.f}, q0 = {0.f,0.f,0.f,0.f};
    f32x4 p1 = {0.f,0.f,0.f,0.f}, q1 = {0.f,0.f,0.f,0.f};
    p0 = MFMA_B16(ah0, w1h[0][0], p0);  q0 = MFMA_B16(ah1, w1h[0][1], q0);
    p1 = MFMA_B16(ah0, w1h[1][0], p1);  q1 = MFMA_B16(ah1, w1h[1][1], q1);
    p0 = MFMA_B16(ah0, w1l[0][0], p0);  q0 = MFMA_B16(ah1, w1l[0][1], q0);
    p1 = MFMA_B16(ah0, w1l[1][0], p1);  q1 = MFMA_B16(ah1, w1l[1][1], q1);
    p0 = MFMA_B16(al0, w1h[0][0], p0);  q0 = MFMA_B16(al1, w1h[0][1], q0);
    p1 = MFMA_B16(al0, w1h[1][0], p1);  q1 = MFMA_B16(al1, w1h[1][1], q1);
    f32x4 h0 = p0 + q0, h1 = p1 + q1;
#pragma unroll
    for (int r = 0; r < 4; ++r) {
      float th = tanh_fast(h0[r] + b1v[0]);
      __bf16 hi = (__bf16)th;
      Hh[hoff[0][r]] = hi;
      Hl[hoff[0][r]] = (__bf16)(th - (float)hi);
    }
#pragma unroll
    for (int r = 0; r < 4; ++r) {
      float th = tanh_fast(h1[r] + b1v[1]);
      __bf16 hi = (__bf16)th;
      Hh[hoff[1][r]] = hi;
      Hl[hoff[1][r]] = (__bf16)(th - (float)hi);
    }
    __syncthreads();                      // bar2: H ready
    f32x4 aA = {0.f,0.f,0.f,0.f}, aB = {0.f,0.f,0.f,0.f}, aC = {0.f,0.f,0.f,0.f};
#pragma unroll
    for (int ks = 0; ks < 8; ++ks) {
      bf16x8 ah = *(const bf16x8*)&Hh[ks*512 + physL*8];
      bf16x8 al = *(const bf16x8*)&Hl[ks*512 + physL*8];
      aA = MFMA_B16(ah, w2h[ks], aA);
      aB = MFMA_B16(ah, w2l[ks], aB);
      aC = MFMA_B16(al, w2h[ks], aC);
    }
    return (aA + aB) + aC + splat4(b2v); // identical in pair (same inputs/order)
  };

  for (int iv = 0; iv < T_SAVE-1; ++iv) {
    const float h = (ts_s[iv+1] - ts_s[iv]) / (float)nsub;
    const f32x4 h4 = splat4(h);
    for (int sub = 0; sub < nsub; ++sub) {
      f32x4 k1 = feval();
      ysv = y4 + h4 * (splat4(A21f) * k1);
      f32x4 k2 = feval();
      {
        f32x4 t = splat4(A31f)*k1 + splat4(A32f)*k2;
        ysv = y4 + h4 * t;
      }
      f32x4 k3 = feval();
      {
        f32x4 t = splat4(A41f)*k1 + splat4(A42f)*k2 + splat4(A43f)*k3;
        ysv = y4 + h4 * t;
      }
      f32x4 k4 = feval();
      {
        f32x4 t = splat4(A51f)*k1 + splat4(A52f)*k2 + splat4(A53f)*k3
                + splat4(A54f)*k4;
        ysv = y4 + h4 * t;
      }
      f32x4 k5 = feval();
      {
        f32x4 t = splat4(A61f)*k1 + splat4(A62f)*k2 + splat4(A63f)*k3
                + splat4(A64f)*k4 + splat4(A65f)*k5;
        ysv = y4 + h4 * t;
      }
      f32x4 k6 = feval();
      {
        f32x4 t = splat4(B1f)*k1 + splat4(B2f)*k2 + splat4(B3f)*k3
                + splat4(B4f)*k4 + splat4(B5f)*k5 + splat4(B6f)*k6;
        y4 = y4 + h4 * t;
        ysv = y4;
      }
    }
    if (hiW) {
#pragma unroll
      for (int s = 0; s < 4; ++s) {
        int row = rowbase + 4*g + s;
        out[(size_t)row*(T_SAVE*DIM) + (size_t)(iv+1)*DIM + d_] = y4[s];
      }
    }
  }
}

extern "C" void kernel_launch(void* const* d_in, const int* in_sizes, int n_in,
                              void* d_out, int out_size, void* d_ws, size_t ws_size,
                              hipStream_t stream) {
  const float* y0 = (const float*)d_in[0];
  const float* ts = (const float*)d_in[1];
  const float* W1 = (const float*)d_in[2];
  const float* b1 = (const float*)d_in[3];
  const float* W2 = (const float*)d_in[4];
  const float* b2 = (const float*)d_in[5];
  const int* nsub = (const int*)d_in[6];
  float* out = (float*)d_out;

  const int Bnum = in_sizes[0] / DIM;       // 4096
  const int nblocks = Bnum / 16;            // 256 workgroups, one per CU
  node_tsit5_kernel<<<nblocks, 512, 0, stream>>>(y0, ts, W1, b1, W2, b2, nsub, out);
}

// Round 5
// 7348.359 us; speedup vs baseline: 1.0004x; 1.0004x over previous
//
#include <hip/hip_runtime.h>
#include <hip/hip_bf16.h>

typedef __bf16 bf16x8 __attribute__((ext_vector_type(8)));
typedef float f32x4 __attribute__((ext_vector_type(4)));
typedef unsigned int u32;
typedef u32 u32x4 __attribute__((ext_vector_type(4)));

#define MFMA_B16(a,b,c) __builtin_amdgcn_mfma_f32_16x16x32_bf16((a),(b),(c),0,0,0)

// Tsit5 coefficients
#define A21f 0.161f
#define A31f (-0.008480655492356989f)
#define A32f 0.335480655492357f
#define A41f 2.8971530571054935f
#define A42f (-6.359448489975075f)
#define A43f 4.3622954328695815f
#define A51f 5.325864828439257f
#define A52f (-11.748883564062828f)
#define A53f 7.4955393428898365f
#define A54f (-0.09249506636175525f)
#define A61f 5.86145544294642f
#define A62f (-12.92096931784711f)
#define A63f 8.159367898576159f
#define A64f (-0.071584973281401f)
#define A65f (-0.028269050394068383f)
#define B1f 0.09646076681806523f
#define B2f 0.01f
#define B3f 0.4798896504144996f
#define B4f 1.379008574103742f
#define B5f (-3.290069515436081f)
#define B6f 2.324710524099774f

constexpr int T_SAVE = 128;
constexpr int DIM = 64;
constexpr int HID = 256;

__device__ __forceinline__ float fast_exp2(float x){
#if __has_builtin(__builtin_amdgcn_exp2f)
  return __builtin_amdgcn_exp2f(x);
#else
  return exp2f(x);
#endif
}
__device__ __forceinline__ float fast_rcp(float x){
#if __has_builtin(__builtin_amdgcn_rcpf)
  return __builtin_amdgcn_rcpf(x);
#else
  return 1.0f / x;
#endif
}
__device__ __forceinline__ float tanh_fast(float x){
  float t = fast_exp2(x * 2.8853900817779268f);
  return 1.0f - 2.0f * fast_rcp(t + 1.0f);
}
__device__ __forceinline__ f32x4 splat4(float x){ return f32x4{x,x,x,x}; }

// pack value as u32: low16 = hi-bf16 (mantissa-truncated), high16 = lo-bf16 (RNE)
__device__ __forceinline__ u32 pack_hl(float x){
  u32 xu = __float_as_uint(x);
  float lo = x - __uint_as_float(xu & 0xFFFF0000u);
  __bf16 lb = (__bf16)lo;
  unsigned short ls; __builtin_memcpy(&ls, &lb, 2);
  return ((u32)ls << 16) | (xu >> 16);
}

// p[0..7] packed dwords (elements j=0..7) -> pure-hi and pure-lo bf16x8 frags
__device__ __forceinline__ void unpack_hl(const u32* p, bf16x8& ah, bf16x8& al){
  union { u32 d[4]; bf16x8 v; } H, L;
#pragma unroll
  for (int j = 0; j < 4; ++j) {
    H.d[j] = __builtin_amdgcn_perm(p[2*j+1], p[2*j], 0x05040100u);
    L.d[j] = __builtin_amdgcn_perm(p[2*j+1], p[2*j], 0x07060302u);
  }
  ah = H.v; al = L.v;
}

// 8 waves (512 thr)/block, 16 batch rows/block, 2 waves/SIMD.
// Packed hi|lo u32 staging for Y and H (b32 writes, b128 reads + v_perm unpack).
// Waves 0-3: sole owners of RK state for col-tile w; also L1 tiles {2w,2w+1}
//            and L2 K-half 0. Waves 4-7: L1 tiles {2w,2w+1}, L2 K-half 1 for
//            col-tile w-4, write Pex partial. 3 barriers/feval.
__global__ __launch_bounds__(512, 2)
void node_tsit5_kernel(const float* __restrict__ y0, const float* __restrict__ ts,
                       const float* __restrict__ W1g, const float* __restrict__ b1g,
                       const float* __restrict__ W2g, const float* __restrict__ b2g,
                       const int* __restrict__ nsub_p, float* __restrict__ out)
{
  const int tid = (int)threadIdx.x;
  const int w   = tid >> 6;   // wave 0..7
  const int l   = tid & 63;
  const int c   = l & 15;
  const int g   = l >> 4;
  const bool state = (w < 4);
  const int tile = state ? w : (w - 4);   // L2 output col-tile
  const int kh   = state ? 0 : 1;         // L2 K-half
  const int rowbase = (int)blockIdx.x * 16;

  __shared__ __align__(16) u32 Yp[1024];      // 2 slices x 512 dwords (4 KB)
  __shared__ __align__(16) u32 Hp[4096];      // 8 slices x 512 dwords (16 KB)
  __shared__ __align__(16) f32x4 Pex[256];    // 4 tiles x 64 lanes (4 KB)
  __shared__ float ts_s[T_SAVE];

  if (tid < T_SAVE) ts_s[tid] = ts[tid];

  const int nsub = nsub_p[0];

  // ---- weight fragments, pre-split hi/lo bf16, in registers ----
  bf16x8 w1h[2][2], w1l[2][2];     // [tile nt][k-slice s]
#pragma unroll
  for (int nt = 0; nt < 2; ++nt) {
    const int col = (2*w + nt)*16 + c;
#pragma unroll
    for (int s = 0; s < 2; ++s)
#pragma unroll
      for (int j = 0; j < 8; ++j) {
        float v = W1g[(s*32 + g*8 + j)*HID + col];
        __bf16 hi = (__bf16)v;
        w1h[nt][s][j] = hi;
        w1l[nt][s][j] = (__bf16)(v - (float)hi);
      }
  }
  bf16x8 w2h[4], w2l[4];           // own K-half, own col-tile
#pragma unroll
  for (int i = 0; i < 4; ++i) {
    const int ks = 4*kh + i;
#pragma unroll
    for (int j = 0; j < 8; ++j) {
      float v = W2g[(ks*32 + g*8 + j)*DIM + (tile*16 + c)];
      __bf16 hi = (__bf16)v;
      w2h[i][j] = hi;
      w2l[i][j] = (__bf16)(v - (float)hi);
    }
  }
  float b1v[2];
#pragma unroll
  for (int nt = 0; nt < 2; ++nt) b1v[nt] = b1g[(2*w + nt)*16 + c];
  const float b2v = b2g[tile*16 + c];

  // reader: lane-XOR swizzled contiguous 8-dword block
  const int rdDw = (l ^ ((l >> 2) & 3)) * 8;

  // writer dword offsets (XOR-swizzled: bank = 8*(r^g) + (c&7), conflict-free)
  int hoffDw[2][4];
#pragma unroll
  for (int nt = 0; nt < 2; ++nt)
#pragma unroll
    for (int r = 0; r < 4; ++r)
      hoffDw[nt][r] = w*512 + (nt*2 + (c>>3))*128 + 32*g + 8*(r ^ g) + (c & 7);
  int yoffDw[4];
#pragma unroll
  for (int s = 0; s < 4; ++s)
    yoffDw[s] = (w>>1)*512 + ((w&1)*2 + (c>>3))*128 + 32*g + 8*(s ^ g) + (c & 7);

  // ---- initial state (waves 0-3 only); emit t=0 ----
  const int d_ = tile*16 + c;
  f32x4 y4 = {0.f,0.f,0.f,0.f};
  if (state) {
#pragma unroll
    for (int s = 0; s < 4; ++s) {
      int row = rowbase + 4*g + s;
      y4[s] = y0[row*DIM + d_];
      out[(size_t)row*(T_SAVE*DIM) + d_] = y4[s];
    }
  }
  __syncthreads();   // ts_s ready

  f32x4 ysv = y4;

  auto feval = [&]() -> f32x4 {
    if (state) {
#pragma unroll
      for (int s = 0; s < 4; ++s) Yp[yoffDw[s]] = pack_hl(ysv[s]);
    }
    __syncthreads();                       // bar1: Y ready
    u32 py[8], pz[8];
    *(u32x4*)&py[0] = *(const u32x4*)&Yp[rdDw];
    *(u32x4*)&py[4] = *(const u32x4*)&Yp[rdDw + 4];
    *(u32x4*)&pz[0] = *(const u32x4*)&Yp[512 + rdDw];
    *(u32x4*)&pz[4] = *(const u32x4*)&Yp[512 + rdDw + 4];
    bf16x8 ah0, al0, ah1, al1;
    unpack_hl(py, ah0, al0);
    unpack_hl(pz, ah1, al1);
    // L1: 2 tiles x (3-term split x 2 k-slices), 4 chains of depth 3
    f32x4 t0a={0.f,0.f,0.f,0.f}, t0b={0.f,0.f,0.f,0.f};
    f32x4 t1a={0.f,0.f,0.f,0.f}, t1b={0.f,0.f,0.f,0.f};
    t0a = MFMA_B16(ah0, w1h[0][0], t0a);  t0b = MFMA_B16(ah1, w1h[0][1], t0b);
    t1a = MFMA_B16(ah0, w1h[1][0], t1a);  t1b = MFMA_B16(ah1, w1h[1][1], t1b);
    t0a = MFMA_B16(ah0, w1l[0][0], t0a);  t0b = MFMA_B16(ah1, w1l[0][1], t0b);
    t1a = MFMA_B16(ah0, w1l[1][0], t1a);  t1b = MFMA_B16(ah1, w1l[1][1], t1b);
    t0a = MFMA_B16(al0, w1h[0][0], t0a);  t0b = MFMA_B16(al1, w1h[0][1], t0b);
    t1a = MFMA_B16(al0, w1h[1][0], t1a);  t1b = MFMA_B16(al1, w1h[1][1], t1b);
    f32x4 ht0 = t0a + t0b, ht1 = t1a + t1b;
#pragma unroll
    for (int r = 0; r < 4; ++r)
      Hp[hoffDw[0][r]] = pack_hl(tanh_fast(ht0[r] + b1v[0]));
#pragma unroll
    for (int r = 0; r < 4; ++r)
      Hp[hoffDw[1][r]] = pack_hl(tanh_fast(ht1[r] + b1v[1]));
    __syncthreads();                       // bar2: H ready
    u32 ph[4][8];
#pragma unroll
    for (int i = 0; i < 4; ++i) {
      const int ks = 4*kh + i;
      *(u32x4*)&ph[i][0] = *(const u32x4*)&Hp[ks*512 + rdDw];
      *(u32x4*)&ph[i][4] = *(const u32x4*)&Hp[ks*512 + rdDw + 4];
    }
    // L2: own K-half, 3 chains of depth 4
    f32x4 aA={0.f,0.f,0.f,0.f}, aB={0.f,0.f,0.f,0.f}, aC={0.f,0.f,0.f,0.f};
#pragma unroll
    for (int i = 0; i < 4; ++i) {
      bf16x8 ah, al;
      unpack_hl(ph[i], ah, al);
      aA = MFMA_B16(ah, w2h[i], aA);
      aB = MFMA_B16(ah, w2l[i], aB);
      aC = MFMA_B16(al, w2h[i], aC);
    }
    f32x4 part = (aA + aB) + aC;
    if (!state) Pex[tile*64 + l] = part;
    __syncthreads();                       // bar3: partials ready
    f32x4 kout = {0.f,0.f,0.f,0.f};
    if (state) {
      f32x4 q = Pex[tile*64 + l];
      kout = (part + q) + splat4(b2v);
    }
    return kout;
  };

  for (int iv = 0; iv < T_SAVE-1; ++iv) {
    const float h = (ts_s[iv+1] - ts_s[iv]) / (float)nsub;
    const f32x4 h4 = splat4(h);
    for (int sub = 0; sub < nsub; ++sub) {
      f32x4 k1 = feval();
      if (state) ysv = y4 + h4 * (splat4(A21f) * k1);
      f32x4 k2 = feval();
      if (state) {
        f32x4 t = splat4(A31f)*k1 + splat4(A32f)*k2;
        ysv = y4 + h4 * t;
      }
      f32x4 k3 = feval();
      if (state) {
        f32x4 t = splat4(A41f)*k1 + splat4(A42f)*k2 + splat4(A43f)*k3;
        ysv = y4 + h4 * t;
      }
      f32x4 k4 = feval();
      if (state) {
        f32x4 t = splat4(A51f)*k1 + splat4(A52f)*k2 + splat4(A53f)*k3
                + splat4(A54f)*k4;
        ysv = y4 + h4 * t;
      }
      f32x4 k5 = feval();
      if (state) {
        f32x4 t = splat4(A61f)*k1 + splat4(A62f)*k2 + splat4(A63f)*k3
                + splat4(A64f)*k4 + splat4(A65f)*k5;
        ysv = y4 + h4 * t;
      }
      f32x4 k6 = feval();
      if (state) {
        f32x4 t = splat4(B1f)*k1 + splat4(B2f)*k2 + splat4(B3f)*k3
                + splat4(B4f)*k4 + splat4(B5f)*k5 + splat4(B6f)*k6;
        y4 = y4 + h4 * t;
        ysv = y4;
      }
    }
    if (state) {
#pragma unroll
      for (int s = 0; s < 4; ++s) {
        int row = rowbase + 4*g + s;
        out[(size_t)row*(T_SAVE*DIM) + (size_t)(iv+1)*DIM + d_] = y4[s];
      }
    }
  }
}

extern "C" void kernel_launch(void* const* d_in, const int* in_sizes, int n_in,
                              void* d_out, int out_size, void* d_ws, size_t ws_size,
                              hipStream_t stream) {
  const float* y0 = (const float*)d_in[0];
  const float* ts = (const float*)d_in[1];
  const float* W1 = (const float*)d_in[2];
  const float* b1 = (const float*)d_in[3];
  const float* W2 = (const float*)d_in[4];
  const float* b2 = (const float*)d_in[5];
  const int* nsub = (const int*)d_in[6];
  float* out = (float*)d_out;

  const int Bnum = in_sizes[0] / DIM;       // 4096
  const int nblocks = Bnum / 16;            // 256 workgroups, one per CU
  node_tsit5_kernel<<<nblocks, 512, 0, stream>>>(y0, ts, W1, b1, W2, b2, nsub, out);
}